// Round 1
// baseline (846.708 us; speedup 1.0000x reference)
//
#include <hip/hip_runtime.h>

#define CH 128

// ---------------------------------------------------------------- utilities

__device__ __forceinline__ int edge_at(const void* ei, long long i, int is64) {
  if (is64) return (int)((const long long*)ei)[i];
  return ((const int*)ei)[i];
}

// Detect whether edge_index is stored as int64 (odd 32-bit words all zero)
__global__ void k_detect(const int* ei, int* flag) {
  if (blockIdx.x == 0 && threadIdx.x == 0) {
    int is64 = 1;
    for (int k = 1; k < 128; k += 2)
      if (ei[k] != 0) { is64 = 0; break; }
    *flag = is64;
  }
}

__global__ void k_init(int* counts, float* S, int N) {
  int i = blockIdx.x * 256 + threadIdx.x;
  if (i < N) counts[i] = 0;
  if (i < CH) S[i] = 0.f;
}

__global__ void k_hist(const void* ei, const int* flag, int* counts, int E, int N) {
  int e = blockIdx.x * 256 + threadIdx.x;
  if (e >= E) return;
  int f = *flag;
  int c = edge_at(ei, (long long)E + e, f);
  if ((unsigned)c < (unsigned)N) atomicAdd(&counts[c], 1);
}

__global__ void k_dinv(const int* counts, float* dinv, int N) {
  int i = blockIdx.x * 256 + threadIdx.x;
  if (i < N) dinv[i] = rsqrtf((float)(counts[i] + 1));  // +1 self-loop
}

// Block-level exclusive scan (256 elems/block) producing block sums
__global__ void k_scan1(const int* counts, int* rowptr, int* bsum, int N) {
  __shared__ int tmp[256];
  int tid = threadIdx.x, i = blockIdx.x * 256 + tid;
  int v = (i < N) ? counts[i] : 0;
  tmp[tid] = v;
  __syncthreads();
  for (int off = 1; off < 256; off <<= 1) {
    int t = (tid >= off) ? tmp[tid - off] : 0;
    __syncthreads();
    tmp[tid] += t;
    __syncthreads();
  }
  if (i < N) rowptr[i] = tmp[tid] - v;
  if (tid == 255) bsum[blockIdx.x] = tmp[255];
}

__global__ void k_scan2(const int* bsum, int* boff, int nb) {
  __shared__ int tmp[256];
  int tid = threadIdx.x;
  int v = (tid < nb) ? bsum[tid] : 0;
  tmp[tid] = v;
  __syncthreads();
  for (int off = 1; off < 256; off <<= 1) {
    int t = (tid >= off) ? tmp[tid - off] : 0;
    __syncthreads();
    tmp[tid] += t;
    __syncthreads();
  }
  boff[tid] = tmp[tid] - v;
}

__global__ void k_scan3(int* rowptr, int* cursor, const int* boff, int N, int E) {
  int i = blockIdx.x * 256 + threadIdx.x;
  if (i < N) {
    int r = rowptr[i] + boff[i >> 8];
    rowptr[i] = r;
    cursor[i] = r;
  } else if (i == N) {
    rowptr[N] = E;
  }
}

__global__ void k_scatter(const void* ei, const int* flag, int* cursor, int* src,
                          int E, int N) {
  int e = blockIdx.x * 256 + threadIdx.x;
  if (e >= E) return;
  int f = *flag;
  int r = edge_at(ei, e, f);
  int c = edge_at(ei, (long long)E + e, f);
  if ((unsigned)c < (unsigned)N && (unsigned)r < (unsigned)N) {
    int p = atomicAdd(&cursor[c], 1);
    src[p] = r;
  }
}

// ---------------------------------------------------------------- GEMM
// C[r,:] = dinv[r] * (A[r,:] @ W), A: [N,128], W: [128,128]
// 64x64 tile, 256 threads, 4x4 microtile, exactly 64 KB LDS.
// k index staggered by ty*33 so A-reads hit 4 distinct banks (broadcast) and
// B-reads stay uniform — no pad needed.
__global__ __launch_bounds__(256) void k_gemm(const float* __restrict__ A,
                                              const float* __restrict__ W,
                                              const float* __restrict__ dinv,
                                              float* __restrict__ C, int N) {
  __shared__ float As[64][128];
  __shared__ float Bs[128][64];
  int tid = threadIdx.x;
  int row0 = blockIdx.x * 64;
  int col0 = blockIdx.y * 64;

  {
    int k4 = tid & 31, m = tid >> 5;
    for (int mm = m; mm < 64; mm += 8) {
      int gr = row0 + mm;
      float4 v = make_float4(0.f, 0.f, 0.f, 0.f);
      if (gr < N) v = ((const float4*)A)[(size_t)gr * 32 + k4];
      *(float4*)&As[mm][k4 * 4] = v;
    }
    int n4 = tid & 15, kr = tid >> 4;
    for (int kk = kr; kk < 128; kk += 16) {
      float4 v = ((const float4*)W)[(size_t)kk * 32 + (col0 >> 2) + n4];
      *(float4*)&Bs[kk][n4 * 4] = v;
    }
  }
  __syncthreads();

  int tx = tid & 15, ty = tid >> 4;
  int m0 = ty * 4, n0 = tx * 4;
  float acc[4][4] = {};
#pragma unroll 8
  for (int k = 0; k < 128; ++k) {
    int kk = (k + ty * 33) & 127;  // bank-conflict stagger; sum order only
    float a0 = As[m0 + 0][kk];
    float a1 = As[m0 + 1][kk];
    float a2 = As[m0 + 2][kk];
    float a3 = As[m0 + 3][kk];
    float4 b = *(const float4*)&Bs[kk][n0];
    acc[0][0] += a0 * b.x; acc[0][1] += a0 * b.y; acc[0][2] += a0 * b.z; acc[0][3] += a0 * b.w;
    acc[1][0] += a1 * b.x; acc[1][1] += a1 * b.y; acc[1][2] += a1 * b.z; acc[1][3] += a1 * b.w;
    acc[2][0] += a2 * b.x; acc[2][1] += a2 * b.y; acc[2][2] += a2 * b.z; acc[2][3] += a2 * b.w;
    acc[3][0] += a3 * b.x; acc[3][1] += a3 * b.y; acc[3][2] += a3 * b.z; acc[3][3] += a3 * b.w;
  }

#pragma unroll
  for (int i = 0; i < 4; ++i) {
    int gr = row0 + m0 + i;
    if (gr < N) {
      float s = dinv[gr];
      float4 o = make_float4(acc[i][0] * s, acc[i][1] * s, acc[i][2] * s, acc[i][3] * s);
      *(float4*)&C[(size_t)gr * CH + col0 + n0] = o;
    }
  }
}

// ---------------------------------------------------------------- aggregate
// MODE 0: out[c,:] = relu(dinv[c]*(hhat[c,:] + sum_{r in CSR[c]} hhat[r,:]) + bias)
// MODE 1: S[:] += dinv[c]*(hhat[c,:] + sum ...)   (global sum for mean-pool)
template <int MODE>
__global__ __launch_bounds__(256) void k_agg(const float* __restrict__ hhat,
                                             const float* __restrict__ dinv,
                                             const int* __restrict__ rowptr,
                                             const int* __restrict__ src,
                                             const float* __restrict__ bias,
                                             float* __restrict__ out,
                                             float* __restrict__ S, int N) {
  int ch = threadIdx.x;  // 0..127
  float gsum = 0.f;
  for (int c = blockIdx.x * 2 + threadIdx.y; c < N; c += gridDim.x * 2) {
    float acc = hhat[(size_t)c * CH + ch];  // self-loop term
    int je = rowptr[c + 1];
    int j = rowptr[c];
    for (; j + 4 <= je; j += 4) {
      int r0 = src[j], r1 = src[j + 1], r2 = src[j + 2], r3 = src[j + 3];
      float v0 = hhat[(size_t)r0 * CH + ch];
      float v1 = hhat[(size_t)r1 * CH + ch];
      float v2 = hhat[(size_t)r2 * CH + ch];
      float v3 = hhat[(size_t)r3 * CH + ch];
      acc += v0 + v1 + v2 + v3;
    }
    for (; j < je; ++j) acc += hhat[(size_t)src[j] * CH + ch];
    float v = acc * dinv[c];
    if (MODE == 0) {
      v += bias[ch];
      v = fmaxf(v, 0.f);
      out[(size_t)c * CH + ch] = v;
    } else {
      gsum += v;
    }
  }
  if (MODE == 1) atomicAdd(&S[ch], gsum);
}

// ---------------------------------------------------------------- epilogue
__global__ void k_final(const float* __restrict__ S, const float* __restrict__ b3,
                        const float* __restrict__ Wl, const float* __restrict__ bl,
                        float* __restrict__ out, float invN) {
  __shared__ float red[CH];
  int t = threadIdx.x;
  float g = S[t] * invN + b3[t];
  red[t] = g * Wl[t];
  __syncthreads();
  for (int off = 64; off > 0; off >>= 1) {
    if (t < off) red[t] += red[t + off];
    __syncthreads();
  }
  if (t == 0) out[0] = 1.f / (1.f + expf(-(red[0] + bl[0])));
}

// ---------------------------------------------------------------- launch

extern "C" void kernel_launch(void* const* d_in, const int* in_sizes, int n_in,
                              void* d_out, int out_size, void* d_ws, size_t ws_size,
                              hipStream_t stream) {
  const float* x  = (const float*)d_in[0];
  const void*  ei = d_in[1];
  const float* W1 = (const float*)d_in[3];
  const float* b1 = (const float*)d_in[4];
  const float* W2 = (const float*)d_in[5];
  const float* b2 = (const float*)d_in[6];
  const float* W3 = (const float*)d_in[7];
  const float* b3 = (const float*)d_in[8];
  const float* Wl = (const float*)d_in[9];
  const float* bl = (const float*)d_in[10];
  float* out = (float*)d_out;

  const int N = in_sizes[0] / CH;
  const int E = in_sizes[1] / 2;

  char* ws = (char*)d_ws;
  size_t off = 0;
  auto alloc = [&](size_t bytes) -> void* {
    void* p = ws + off;
    off += (bytes + 511) & ~(size_t)511;
    return p;
  };
  int*   flag   = (int*)alloc(4);
  int*   counts = (int*)alloc((size_t)N * 4);
  float* dinv   = (float*)alloc((size_t)N * 4);
  int*   rowptr = (int*)alloc((size_t)(N + 1) * 4);
  int*   cursor = (int*)alloc((size_t)N * 4);
  int*   bsum   = (int*)alloc(256 * 4);
  int*   boff   = (int*)alloc(256 * 4);
  float* S      = (float*)alloc(CH * 4);
  int*   src    = (int*)alloc((size_t)E * 4);
  float* hbuf   = (float*)alloc((size_t)N * CH * 4);
  float* xbuf   = (float*)alloc((size_t)N * CH * 4);

  const int nbN = (N + 255) / 256;
  const int nbE = (E + 255) / 256;

  // ---- preprocessing (shared norm + CSR by col)
  k_detect<<<1, 64, 0, stream>>>((const int*)ei, flag);
  k_init<<<nbN, 256, 0, stream>>>(counts, S, N);
  k_hist<<<nbE, 256, 0, stream>>>(ei, flag, counts, E, N);
  k_dinv<<<nbN, 256, 0, stream>>>(counts, dinv, N);
  k_scan1<<<nbN, 256, 0, stream>>>(counts, rowptr, bsum, N);
  k_scan2<<<1, 256, 0, stream>>>(bsum, boff, nbN);
  k_scan3<<<(N + 1 + 255) / 256, 256, 0, stream>>>(rowptr, cursor, boff, N, E);
  k_scatter<<<nbE, 256, 0, stream>>>(ei, flag, cursor, src, E, N);

  // ---- three convs
  dim3 ggrid((N + 63) / 64, 2);
  dim3 ablk(CH, 2);
  dim3 agrid((N + 1) / 2);

  k_gemm<<<ggrid, 256, 0, stream>>>(x, W1, dinv, hbuf, N);
  k_agg<0><<<agrid, ablk, 0, stream>>>(hbuf, dinv, rowptr, src, b1, xbuf, nullptr, N);
  k_gemm<<<ggrid, 256, 0, stream>>>(xbuf, W2, dinv, hbuf, N);
  k_agg<0><<<agrid, ablk, 0, stream>>>(hbuf, dinv, rowptr, src, b2, xbuf, nullptr, N);
  k_gemm<<<ggrid, 256, 0, stream>>>(xbuf, W3, dinv, hbuf, N);
  k_agg<1><<<dim3(1024), ablk, 0, stream>>>(hbuf, dinv, rowptr, src, nullptr, nullptr, S, N);

  k_final<<<1, CH, 0, stream>>>(S, b3, Wl, bl, out, 1.0f / (float)N);
}

// Round 3
// 715.188 us; speedup vs baseline: 1.1839x; 1.1839x over previous
//
#include <hip/hip_runtime.h>

#define CH 128

// ---------------------------------------------------------------- utilities

__device__ __forceinline__ int edge_at(const void* ei, long long i, int is64) {
  if (is64) return (int)((const long long*)ei)[i];
  return ((const int*)ei)[i];
}

// Detect whether edge_index is stored as int64 (odd 32-bit words all zero)
__global__ void k_detect(const int* ei, int* flag) {
  if (blockIdx.x == 0 && threadIdx.x == 0) {
    int is64 = 1;
    for (int k = 1; k < 128; k += 2)
      if (ei[k] != 0) { is64 = 0; break; }
    *flag = is64;
  }
}

__global__ void k_init(int* counts, float* S, int N) {
  int i = blockIdx.x * 256 + threadIdx.x;
  if (i < N) counts[i] = 0;
  if (i < CH) S[i] = 0.f;
}

__global__ void k_hist(const void* ei, const int* flag, int* counts, int E, int N) {
  int e = blockIdx.x * 256 + threadIdx.x;
  if (e >= E) return;
  int f = *flag;
  int c = edge_at(ei, (long long)E + e, f);
  if ((unsigned)c < (unsigned)N) atomicAdd(&counts[c], 1);
}

// dinv + seed w with the self-loop term
__global__ void k_dinv(const int* counts, float* dinv, float* w, int N) {
  int i = blockIdx.x * 256 + threadIdx.x;
  if (i < N) {
    float d = rsqrtf((float)(counts[i] + 1));  // +1 self-loop
    dinv[i] = d;
    w[i] = d;
  }
}

// w[r] += sum over edges r->c of dinv[c]
__global__ void k_w(const void* ei, const int* flag, const float* dinv, float* w,
                    int E, int N) {
  int e = blockIdx.x * 256 + threadIdx.x;
  if (e >= E) return;
  int f = *flag;
  int r = edge_at(ei, e, f);
  int c = edge_at(ei, (long long)E + e, f);
  if ((unsigned)c < (unsigned)N && (unsigned)r < (unsigned)N)
    atomicAdd(&w[r], dinv[c]);
}

// Block-level exclusive scan (256 elems/block) producing block sums
__global__ void k_scan1(const int* counts, int* rowptr, int* bsum, int N) {
  __shared__ int tmp[256];
  int tid = threadIdx.x, i = blockIdx.x * 256 + tid;
  int v = (i < N) ? counts[i] : 0;
  tmp[tid] = v;
  __syncthreads();
  for (int off = 1; off < 256; off <<= 1) {
    int t = (tid >= off) ? tmp[tid - off] : 0;
    __syncthreads();
    tmp[tid] += t;
    __syncthreads();
  }
  if (i < N) rowptr[i] = tmp[tid] - v;
  if (tid == 255) bsum[blockIdx.x] = tmp[255];
}

__global__ void k_scan2(const int* bsum, int* boff, int nb) {
  __shared__ int tmp[256];
  int tid = threadIdx.x;
  int v = (tid < nb) ? bsum[tid] : 0;
  tmp[tid] = v;
  __syncthreads();
  for (int off = 1; off < 256; off <<= 1) {
    int t = (tid >= off) ? tmp[tid - off] : 0;
    __syncthreads();
    tmp[tid] += t;
    __syncthreads();
  }
  boff[tid] = tmp[tid] - v;
}

__global__ void k_scan3(int* rowptr, int* cursor, const int* boff, int N, int E) {
  int i = blockIdx.x * 256 + threadIdx.x;
  if (i < N) {
    int r = rowptr[i] + boff[i >> 8];
    rowptr[i] = r;
    cursor[i] = r;
  } else if (i == N) {
    rowptr[N] = E;
  }
}

__global__ void k_scatter(const void* ei, const int* flag, int* cursor, int* src,
                          int E, int N) {
  int e = blockIdx.x * 256 + threadIdx.x;
  if (e >= E) return;
  int f = *flag;
  int r = edge_at(ei, e, f);
  int c = edge_at(ei, (long long)E + e, f);
  if ((unsigned)c < (unsigned)N && (unsigned)r < (unsigned)N) {
    int p = atomicAdd(&cursor[c], 1);
    src[p] = r;
  }
}

// ---------------------------------------------------------------- GEMM
// C[r,:] = dinv[r] * (A[r,:] @ W), A: [N,128], W: [128,128]
__global__ __launch_bounds__(256) void k_gemm(const float* __restrict__ A,
                                              const float* __restrict__ W,
                                              const float* __restrict__ dinv,
                                              float* __restrict__ C, int N) {
  __shared__ float As[64][128];
  __shared__ float Bs[128][64];
  int tid = threadIdx.x;
  int row0 = blockIdx.x * 64;
  int col0 = blockIdx.y * 64;

  {
    int k4 = tid & 31, m = tid >> 5;
    for (int mm = m; mm < 64; mm += 8) {
      int gr = row0 + mm;
      float4 v = make_float4(0.f, 0.f, 0.f, 0.f);
      if (gr < N) v = ((const float4*)A)[(size_t)gr * 32 + k4];
      *(float4*)&As[mm][k4 * 4] = v;
    }
    int n4 = tid & 15, kr = tid >> 4;
    for (int kk = kr; kk < 128; kk += 16) {
      float4 v = ((const float4*)W)[(size_t)kk * 32 + (col0 >> 2) + n4];
      *(float4*)&Bs[kk][n4 * 4] = v;
    }
  }
  __syncthreads();

  int tx = tid & 15, ty = tid >> 4;
  int m0 = ty * 4, n0 = tx * 4;
  float acc[4][4] = {};
#pragma unroll 8
  for (int k = 0; k < 128; ++k) {
    int kk = (k + ty * 33) & 127;  // bank-conflict stagger; sum order only
    float a0 = As[m0 + 0][kk];
    float a1 = As[m0 + 1][kk];
    float a2 = As[m0 + 2][kk];
    float a3 = As[m0 + 3][kk];
    float4 b = *(const float4*)&Bs[kk][n0];
    acc[0][0] += a0 * b.x; acc[0][1] += a0 * b.y; acc[0][2] += a0 * b.z; acc[0][3] += a0 * b.w;
    acc[1][0] += a1 * b.x; acc[1][1] += a1 * b.y; acc[1][2] += a1 * b.z; acc[1][3] += a1 * b.w;
    acc[2][0] += a2 * b.x; acc[2][1] += a2 * b.y; acc[2][2] += a2 * b.z; acc[2][3] += a2 * b.w;
    acc[3][0] += a3 * b.x; acc[3][1] += a3 * b.y; acc[3][2] += a3 * b.z; acc[3][3] += a3 * b.w;
  }

#pragma unroll
  for (int i = 0; i < 4; ++i) {
    int gr = row0 + m0 + i;
    if (gr < N) {
      float s = dinv[gr];
      float4 o = make_float4(acc[i][0] * s, acc[i][1] * s, acc[i][2] * s, acc[i][3] * s);
      *(float4*)&C[(size_t)gr * CH + col0 + n0] = o;
    }
  }
}

// ---------------------------------------------------------------- aggregate
// out[c,:] = relu(dinv[c]*(hhat[c,:] + sum_{r in CSR[c]} hhat[r,:]) + bias)
// float4 gathers: 32 lanes cover a 512B row; 8 node-slots per 256-thread block
// (2 per wave, half-wave each); unroll-8 -> 8 outstanding dwordx4 per lane.
__global__ __launch_bounds__(256) void k_agg4(const float* __restrict__ hhat,
                                              const float* __restrict__ dinv,
                                              const int* __restrict__ rowptr,
                                              const int* __restrict__ src,
                                              const float* __restrict__ bias,
                                              float* __restrict__ out, int N) {
  const float4* __restrict__ h4 = (const float4*)hhat;
  float4* __restrict__ o4 = (float4*)out;
  int tx = threadIdx.x;  // 0..31: ch quad
  int ty = threadIdx.y;  // 0..7 : node slot
  float4 b = ((const float4*)bias)[tx];

  for (int c = blockIdx.x * 8 + ty; c < N; c += gridDim.x * 8) {
    float4 acc = h4[(size_t)c * 32 + tx];  // self-loop
    int j = rowptr[c];
    int je = rowptr[c + 1];
    for (; j + 8 <= je; j += 8) {
      int r0 = src[j + 0], r1 = src[j + 1], r2 = src[j + 2], r3 = src[j + 3];
      int r4 = src[j + 4], r5 = src[j + 5], r6 = src[j + 6], r7 = src[j + 7];
      float4 v0 = h4[(size_t)r0 * 32 + tx];
      float4 v1 = h4[(size_t)r1 * 32 + tx];
      float4 v2 = h4[(size_t)r2 * 32 + tx];
      float4 v3 = h4[(size_t)r3 * 32 + tx];
      float4 v4 = h4[(size_t)r4 * 32 + tx];
      float4 v5 = h4[(size_t)r5 * 32 + tx];
      float4 v6 = h4[(size_t)r6 * 32 + tx];
      float4 v7 = h4[(size_t)r7 * 32 + tx];
      acc.x += ((v0.x + v1.x) + (v2.x + v3.x)) + ((v4.x + v5.x) + (v6.x + v7.x));
      acc.y += ((v0.y + v1.y) + (v2.y + v3.y)) + ((v4.y + v5.y) + (v6.y + v7.y));
      acc.z += ((v0.z + v1.z) + (v2.z + v3.z)) + ((v4.z + v5.z) + (v6.z + v7.z));
      acc.w += ((v0.w + v1.w) + (v2.w + v3.w)) + ((v4.w + v5.w) + (v6.w + v7.w));
    }
    for (; j < je; ++j) {
      float4 v = h4[(size_t)src[j] * 32 + tx];
      acc.x += v.x; acc.y += v.y; acc.z += v.z; acc.w += v.w;
    }
    float s = dinv[c];
    float4 o;
    o.x = fmaxf(acc.x * s + b.x, 0.f);
    o.y = fmaxf(acc.y * s + b.y, 0.f);
    o.z = fmaxf(acc.z * s + b.z, 0.f);
    o.w = fmaxf(acc.w * s + b.w, 0.f);
    o4[(size_t)c * 32 + tx] = o;
  }
}

// ---------------------------------------------------------------- layer-3 collapse
// u[ch] = sum_c (w[c]*dinv[c]) * x[c,ch]   (streaming, no gather)
__global__ __launch_bounds__(256) void k_usum(const float* __restrict__ x,
                                              const float* __restrict__ w,
                                              const float* __restrict__ dinv,
                                              float* __restrict__ u, int N) {
  __shared__ float red[256];
  int ch = threadIdx.x;  // 0..127
  int ty = threadIdx.y;  // 0..1
  float gs = 0.f;
  for (int c = blockIdx.x * 2 + ty; c < N; c += gridDim.x * 2) {
    gs += (w[c] * dinv[c]) * x[(size_t)c * CH + ch];
  }
  red[ty * CH + ch] = gs;
  __syncthreads();
  if (ty == 0) atomicAdd(&u[ch], red[ch] + red[CH + ch]);
}

// ---------------------------------------------------------------- epilogue
// S = (u/N) @ W3 ; g = S + b3 ; out = sigmoid(g . Wl + bl)
__global__ void k_final(const float* __restrict__ u, const float* __restrict__ W3,
                        const float* __restrict__ b3, const float* __restrict__ Wl,
                        const float* __restrict__ bl, float* __restrict__ out,
                        float invN) {
  __shared__ float us[CH];
  __shared__ float red[CH];
  int t = threadIdx.x;
  us[t] = u[t] * invN;
  __syncthreads();
  float s = 0.f;
  for (int k = 0; k < CH; ++k) s += us[k] * W3[(size_t)k * CH + t];
  float g = s + b3[t];
  red[t] = g * Wl[t];
  __syncthreads();
  for (int off = 64; off > 0; off >>= 1) {
    if (t < off) red[t] += red[t + off];
    __syncthreads();
  }
  if (t == 0) out[0] = 1.f / (1.f + expf(-(red[0] + bl[0])));
}

// ---------------------------------------------------------------- launch

extern "C" void kernel_launch(void* const* d_in, const int* in_sizes, int n_in,
                              void* d_out, int out_size, void* d_ws, size_t ws_size,
                              hipStream_t stream) {
  const float* x  = (const float*)d_in[0];
  const void*  ei = d_in[1];
  const float* W1 = (const float*)d_in[3];
  const float* b1 = (const float*)d_in[4];
  const float* W2 = (const float*)d_in[5];
  const float* b2 = (const float*)d_in[6];
  const float* W3 = (const float*)d_in[7];
  const float* b3 = (const float*)d_in[8];
  const float* Wl = (const float*)d_in[9];
  const float* bl = (const float*)d_in[10];
  float* out = (float*)d_out;

  const int N = in_sizes[0] / CH;
  const int E = in_sizes[1] / 2;

  char* ws = (char*)d_ws;
  size_t off = 0;
  auto alloc = [&](size_t bytes) -> void* {
    void* p = ws + off;
    off += (bytes + 511) & ~(size_t)511;
    return p;
  };
  int*   flag   = (int*)alloc(4);
  int*   counts = (int*)alloc((size_t)N * 4);
  float* dinv   = (float*)alloc((size_t)N * 4);
  float* wvec   = (float*)alloc((size_t)N * 4);
  int*   rowptr = (int*)alloc((size_t)(N + 1) * 4);
  int*   cursor = (int*)alloc((size_t)N * 4);
  int*   bsum   = (int*)alloc(256 * 4);
  int*   boff   = (int*)alloc(256 * 4);
  float* S      = (float*)alloc(CH * 4);
  int*   src    = (int*)alloc((size_t)E * 4);
  float* hbuf   = (float*)alloc((size_t)N * CH * 4);
  float* xbuf   = (float*)alloc((size_t)N * CH * 4);

  const int nbN = (N + 255) / 256;
  const int nbE = (E + 255) / 256;

  // ---- preprocessing (shared norm + CSR by col + layer-3 weight vector)
  k_detect<<<1, 64, 0, stream>>>((const int*)ei, flag);
  k_init<<<nbN, 256, 0, stream>>>(counts, S, N);
  k_hist<<<nbE, 256, 0, stream>>>(ei, flag, counts, E, N);
  k_dinv<<<nbN, 256, 0, stream>>>(counts, dinv, wvec, N);
  k_w<<<nbE, 256, 0, stream>>>(ei, flag, dinv, wvec, E, N);
  k_scan1<<<nbN, 256, 0, stream>>>(counts, rowptr, bsum, N);
  k_scan2<<<1, 256, 0, stream>>>(bsum, boff, nbN);
  k_scan3<<<(N + 1 + 255) / 256, 256, 0, stream>>>(rowptr, cursor, boff, N, E);
  k_scatter<<<nbE, 256, 0, stream>>>(ei, flag, cursor, src, E, N);

  // ---- layers 1 & 2 (GEMM + gather-aggregate)
  dim3 ggrid((N + 63) / 64, 2);
  dim3 ablk(32, 8);
  dim3 agrid((N + 7) / 8);

  k_gemm<<<ggrid, 256, 0, stream>>>(x, W1, dinv, hbuf, N);
  k_agg4<<<agrid, ablk, 0, stream>>>(hbuf, dinv, rowptr, src, b1, xbuf, N);
  k_gemm<<<ggrid, 256, 0, stream>>>(xbuf, W2, dinv, hbuf, N);
  k_agg4<<<agrid, ablk, 0, stream>>>(hbuf, dinv, rowptr, src, b2, xbuf, N);

  // ---- layer 3 collapsed: u = sum_c w*dinv*h2[c,:]; S=(u/N)@W3; sigmoid epilogue
  k_usum<<<256, dim3(CH, 2), 0, stream>>>(xbuf, wvec, dinv, S, N);
  k_final<<<1, CH, 0, stream>>>(S, W3, b3, Wl, bl, out, 1.0f / (float)N);
}

// Round 4
// 574.153 us; speedup vs baseline: 1.4747x; 1.2456x over previous
//
#include <hip/hip_runtime.h>

#define CH 128
#define CHUNK 4096

// ---------------------------------------------------------------- utilities

__device__ __forceinline__ int edge_at(const void* ei, long long i, int is64) {
  if (is64) return (int)((const long long*)ei)[i];
  return ((const int*)ei)[i];
}

// Detect whether edge_index is stored as int64 (odd 32-bit words all zero)
__global__ void k_detect(const int* ei, int* flag) {
  if (blockIdx.x == 0 && threadIdx.x == 0) {
    int is64 = 1;
    for (int k = 1; k < 128; k += 2)
      if (ei[k] != 0) { is64 = 0; break; }
    *flag = is64;
  }
}

__global__ void k_init0(int* bcnt, float* S) {
  int t = threadIdx.x;
  bcnt[t] = 0;
  if (t < CH) S[t] = 0.f;
}

// P1: per-bucket edge counts (bucket = c >> 8), LDS-local then merged
__global__ __launch_bounds__(256) void kb_count(const void* ei, const int* flag,
                                                int* bcnt, int E, int N) {
  __shared__ int hist[256];
  int t = threadIdx.x;
  hist[t] = 0;
  __syncthreads();
  int f = *flag;
  for (int e = blockIdx.x * 256 + t; e < E; e += gridDim.x * 256) {
    int r = edge_at(ei, e, f);
    int c = edge_at(ei, (long long)E + e, f);
    if ((unsigned)r < (unsigned)N && (unsigned)c < (unsigned)N)
      atomicAdd(&hist[c >> 8], 1);
  }
  __syncthreads();
  if (hist[t] > 0) atomicAdd(&bcnt[t], hist[t]);
}

// P2: exclusive scan of bucket counts -> bases + global cursors; rowptr[N]=total
__global__ void kb_scan(const int* bcnt, int* bbase, int* gcursor, int* rowptr,
                        int NB, int N) {
  __shared__ int tmp[256];
  int t = threadIdx.x;
  int v = (t < NB) ? bcnt[t] : 0;
  tmp[t] = v;
  __syncthreads();
  for (int off = 1; off < 256; off <<= 1) {
    int u = (t >= off) ? tmp[t - off] : 0;
    __syncthreads();
    tmp[t] += u;
    __syncthreads();
  }
  int excl = tmp[t] - v;
  bbase[t] = excl;
  gcursor[t] = excl;
  if (t == 255) rowptr[N] = tmp[255];
}

// P3: bucket-sort edges into pairs[] via LDS staging. Each block owns one
// 4096-edge chunk; writes land in contiguous per-bucket runs.
__global__ __launch_bounds__(256) void kb_scatter(const void* ei, const int* flag,
                                                  int* gcursor, int2* pairs,
                                                  int E, int N) {
  __shared__ int hist[256], lbase[256], lcur[256], gbl[256], tmp[256];
  __shared__ int2 stage[CHUNK];
  int t = threadIdx.x;
  int e0 = blockIdx.x * CHUNK;
  int f = *flag;
  hist[t] = 0;
  __syncthreads();
  int rr[16], cc[16];
#pragma unroll
  for (int k = 0; k < 16; ++k) {
    int e = e0 + k * 256 + t;
    rr[k] = 0; cc[k] = -1;
    if (e < E) {
      int r = edge_at(ei, e, f);
      int c = edge_at(ei, (long long)E + e, f);
      if ((unsigned)r < (unsigned)N && (unsigned)c < (unsigned)N) {
        rr[k] = r; cc[k] = c;
        atomicAdd(&hist[c >> 8], 1);
      }
    }
  }
  __syncthreads();
  int v = hist[t];
  tmp[t] = v;
  __syncthreads();
  for (int off = 1; off < 256; off <<= 1) {
    int u = (t >= off) ? tmp[t - off] : 0;
    __syncthreads();
    tmp[t] += u;
    __syncthreads();
  }
  lbase[t] = tmp[t] - v;
  lcur[t] = tmp[t] - v;
  if (v > 0) gbl[t] = atomicAdd(&gcursor[t], v);
  __syncthreads();
#pragma unroll
  for (int k = 0; k < 16; ++k) {
    if (cc[k] >= 0) {
      int b = cc[k] >> 8;
      int pos = atomicAdd(&lcur[b], 1);
      stage[pos] = make_int2(rr[k], cc[k]);
    }
  }
  __syncthreads();
  int n = tmp[255];  // valid edges in this chunk
  for (int i = t; i < n; i += 256) {
    int2 p = stage[i];
    int b = p.y >> 8;
    pairs[gbl[b] + (i - lbase[b])] = p;
  }
}

// P4: per-bucket CSR build. Produces counts (in-degree), rowptr, src — all
// writes localized to the bucket's ~65 KB window; cursor atomics in LDS.
__global__ __launch_bounds__(256) void kb_csr(const int2* __restrict__ pairs,
                                              const int* __restrict__ bcnt,
                                              const int* __restrict__ bbase,
                                              int* counts, int* rowptr, int* src,
                                              int N) {
  __shared__ int hist[256], lbase[256], lcur[256], tmp[256];
  int t = threadIdx.x;
  int b = blockIdx.x;
  int node0 = b << 8;
  int nn = min(256, N - node0);
  int base = bbase[b];
  int cnt = bcnt[b];
  hist[t] = 0;
  __syncthreads();
  for (int j = t; j < cnt; j += 256)
    atomicAdd(&hist[pairs[base + j].y - node0], 1);
  __syncthreads();
  int v = hist[t];
  tmp[t] = v;
  __syncthreads();
  for (int off = 1; off < 256; off <<= 1) {
    int u = (t >= off) ? tmp[t - off] : 0;
    __syncthreads();
    tmp[t] += u;
    __syncthreads();
  }
  lbase[t] = tmp[t] - v;
  lcur[t] = tmp[t] - v;
  __syncthreads();
  if (t < nn) {
    counts[node0 + t] = v;
    rowptr[node0 + t] = base + lbase[t];
  }
  for (int j = t; j < cnt; j += 256) {
    int2 p = pairs[base + j];
    int pos = atomicAdd(&lcur[p.y - node0], 1);
    src[base + pos] = p.x;
  }
}

// dinv + seed w with the self-loop term
__global__ void k_dinv(const int* counts, float* dinv, float* w, int N) {
  int i = blockIdx.x * 256 + threadIdx.x;
  if (i < N) {
    float d = rsqrtf((float)(counts[i] + 1));  // +1 self-loop
    dinv[i] = d;
    w[i] = d;
  }
}

// w[r] += sum over edges r->c of dinv[c]
__global__ void k_w(const void* ei, const int* flag, const float* dinv, float* w,
                    int E, int N) {
  int e = blockIdx.x * 256 + threadIdx.x;
  if (e >= E) return;
  int f = *flag;
  int r = edge_at(ei, e, f);
  int c = edge_at(ei, (long long)E + e, f);
  if ((unsigned)c < (unsigned)N && (unsigned)r < (unsigned)N)
    atomicAdd(&w[r], dinv[c]);
}

// ---------------------------------------------------------------- GEMM
// C[r,:] = dinv[r] * (A[r,:] @ W), A: [N,128], W: [128,128]
__global__ __launch_bounds__(256) void k_gemm(const float* __restrict__ A,
                                              const float* __restrict__ W,
                                              const float* __restrict__ dinv,
                                              float* __restrict__ C, int N) {
  __shared__ float As[64][128];
  __shared__ float Bs[128][64];
  int tid = threadIdx.x;
  int row0 = blockIdx.x * 64;
  int col0 = blockIdx.y * 64;

  {
    int k4 = tid & 31, m = tid >> 5;
    for (int mm = m; mm < 64; mm += 8) {
      int gr = row0 + mm;
      float4 v = make_float4(0.f, 0.f, 0.f, 0.f);
      if (gr < N) v = ((const float4*)A)[(size_t)gr * 32 + k4];
      *(float4*)&As[mm][k4 * 4] = v;
    }
    int n4 = tid & 15, kr = tid >> 4;
    for (int kk = kr; kk < 128; kk += 16) {
      float4 v = ((const float4*)W)[(size_t)kk * 32 + (col0 >> 2) + n4];
      *(float4*)&Bs[kk][n4 * 4] = v;
    }
  }
  __syncthreads();

  int tx = tid & 15, ty = tid >> 4;
  int m0 = ty * 4, n0 = tx * 4;
  float acc[4][4] = {};
#pragma unroll 8
  for (int k = 0; k < 128; ++k) {
    int kk = (k + ty * 33) & 127;  // bank-conflict stagger; sum order only
    float a0 = As[m0 + 0][kk];
    float a1 = As[m0 + 1][kk];
    float a2 = As[m0 + 2][kk];
    float a3 = As[m0 + 3][kk];
    float4 b = *(const float4*)&Bs[kk][n0];
    acc[0][0] += a0 * b.x; acc[0][1] += a0 * b.y; acc[0][2] += a0 * b.z; acc[0][3] += a0 * b.w;
    acc[1][0] += a1 * b.x; acc[1][1] += a1 * b.y; acc[1][2] += a1 * b.z; acc[1][3] += a1 * b.w;
    acc[2][0] += a2 * b.x; acc[2][1] += a2 * b.y; acc[2][2] += a2 * b.z; acc[2][3] += a2 * b.w;
    acc[3][0] += a3 * b.x; acc[3][1] += a3 * b.y; acc[3][2] += a3 * b.z; acc[3][3] += a3 * b.w;
  }

#pragma unroll
  for (int i = 0; i < 4; ++i) {
    int gr = row0 + m0 + i;
    if (gr < N) {
      float s = dinv[gr];
      float4 o = make_float4(acc[i][0] * s, acc[i][1] * s, acc[i][2] * s, acc[i][3] * s);
      *(float4*)&C[(size_t)gr * CH + col0 + n0] = o;
    }
  }
}

// ---------------------------------------------------------------- aggregate
// out[c,:] = relu(dinv[c]*(hhat[c,:] + sum_{r in CSR[c]} hhat[r,:]) + bias)
__global__ __launch_bounds__(256) void k_agg4(const float* __restrict__ hhat,
                                              const float* __restrict__ dinv,
                                              const int* __restrict__ rowptr,
                                              const int* __restrict__ src,
                                              const float* __restrict__ bias,
                                              float* __restrict__ out, int N) {
  const float4* __restrict__ h4 = (const float4*)hhat;
  float4* __restrict__ o4 = (float4*)out;
  int tx = threadIdx.x;  // 0..31: ch quad
  int ty = threadIdx.y;  // 0..7 : node slot
  float4 b = ((const float4*)bias)[tx];

  for (int c = blockIdx.x * 8 + ty; c < N; c += gridDim.x * 8) {
    float4 acc = h4[(size_t)c * 32 + tx];  // self-loop
    int j = rowptr[c];
    int je = rowptr[c + 1];
    for (; j + 8 <= je; j += 8) {
      int r0 = src[j + 0], r1 = src[j + 1], r2 = src[j + 2], r3 = src[j + 3];
      int r4 = src[j + 4], r5 = src[j + 5], r6 = src[j + 6], r7 = src[j + 7];
      float4 v0 = h4[(size_t)r0 * 32 + tx];
      float4 v1 = h4[(size_t)r1 * 32 + tx];
      float4 v2 = h4[(size_t)r2 * 32 + tx];
      float4 v3 = h4[(size_t)r3 * 32 + tx];
      float4 v4 = h4[(size_t)r4 * 32 + tx];
      float4 v5 = h4[(size_t)r5 * 32 + tx];
      float4 v6 = h4[(size_t)r6 * 32 + tx];
      float4 v7 = h4[(size_t)r7 * 32 + tx];
      acc.x += ((v0.x + v1.x) + (v2.x + v3.x)) + ((v4.x + v5.x) + (v6.x + v7.x));
      acc.y += ((v0.y + v1.y) + (v2.y + v3.y)) + ((v4.y + v5.y) + (v6.y + v7.y));
      acc.z += ((v0.z + v1.z) + (v2.z + v3.z)) + ((v4.z + v5.z) + (v6.z + v7.z));
      acc.w += ((v0.w + v1.w) + (v2.w + v3.w)) + ((v4.w + v5.w) + (v6.w + v7.w));
    }
    for (; j < je; ++j) {
      float4 v = h4[(size_t)src[j] * 32 + tx];
      acc.x += v.x; acc.y += v.y; acc.z += v.z; acc.w += v.w;
    }
    float s = dinv[c];
    float4 o;
    o.x = fmaxf(acc.x * s + b.x, 0.f);
    o.y = fmaxf(acc.y * s + b.y, 0.f);
    o.z = fmaxf(acc.z * s + b.z, 0.f);
    o.w = fmaxf(acc.w * s + b.w, 0.f);
    o4[(size_t)c * 32 + tx] = o;
  }
}

// ---------------------------------------------------------------- layer-3 collapse
// u[ch] = sum_c (w[c]*dinv[c]) * x[c,ch]   (streaming, no gather)
__global__ __launch_bounds__(256) void k_usum(const float* __restrict__ x,
                                              const float* __restrict__ w,
                                              const float* __restrict__ dinv,
                                              float* __restrict__ u, int N) {
  __shared__ float red[256];
  int ch = threadIdx.x;  // 0..127
  int ty = threadIdx.y;  // 0..1
  float gs = 0.f;
  for (int c = blockIdx.x * 2 + ty; c < N; c += gridDim.x * 2) {
    gs += (w[c] * dinv[c]) * x[(size_t)c * CH + ch];
  }
  red[ty * CH + ch] = gs;
  __syncthreads();
  if (ty == 0) atomicAdd(&u[ch], red[ch] + red[CH + ch]);
}

// ---------------------------------------------------------------- epilogue
// S = (u/N) @ W3 ; g = S + b3 ; out = sigmoid(g . Wl + bl)
__global__ void k_final(const float* __restrict__ u, const float* __restrict__ W3,
                        const float* __restrict__ b3, const float* __restrict__ Wl,
                        const float* __restrict__ bl, float* __restrict__ out,
                        float invN) {
  __shared__ float us[CH];
  __shared__ float red[CH];
  int t = threadIdx.x;
  us[t] = u[t] * invN;
  __syncthreads();
  float s = 0.f;
  for (int k = 0; k < CH; ++k) s += us[k] * W3[(size_t)k * CH + t];
  float g = s + b3[t];
  red[t] = g * Wl[t];
  __syncthreads();
  for (int off = 64; off > 0; off >>= 1) {
    if (t < off) red[t] += red[t + off];
    __syncthreads();
  }
  if (t == 0) out[0] = 1.f / (1.f + expf(-(red[0] + bl[0])));
}

// ---------------------------------------------------------------- launch

extern "C" void kernel_launch(void* const* d_in, const int* in_sizes, int n_in,
                              void* d_out, int out_size, void* d_ws, size_t ws_size,
                              hipStream_t stream) {
  const float* x  = (const float*)d_in[0];
  const void*  ei = d_in[1];
  const float* W1 = (const float*)d_in[3];
  const float* b1 = (const float*)d_in[4];
  const float* W2 = (const float*)d_in[5];
  const float* b2 = (const float*)d_in[6];
  const float* W3 = (const float*)d_in[7];
  const float* b3 = (const float*)d_in[8];
  const float* Wl = (const float*)d_in[9];
  const float* bl = (const float*)d_in[10];
  float* out = (float*)d_out;

  const int N = in_sizes[0] / CH;
  const int E = in_sizes[1] / 2;
  const int NB = (N + 255) >> 8;  // buckets of 256 nodes (<=256 for N<=65536)

  char* ws = (char*)d_ws;
  size_t off = 0;
  auto alloc = [&](size_t bytes) -> void* {
    void* p = ws + off;
    off += (bytes + 511) & ~(size_t)511;
    return p;
  };
  int*   flag   = (int*)alloc(4);
  int*   counts = (int*)alloc((size_t)N * 4);
  float* dinv   = (float*)alloc((size_t)N * 4);
  float* wvec   = (float*)alloc((size_t)N * 4);
  int*   rowptr = (int*)alloc((size_t)(N + 1) * 4);
  int*   bcnt   = (int*)alloc(256 * 4);
  int*   bbase  = (int*)alloc(256 * 4);
  int*   gcur   = (int*)alloc(256 * 4);
  float* S      = (float*)alloc(CH * 4);
  int*   src    = (int*)alloc((size_t)E * 4);
  float* hbuf   = (float*)alloc((size_t)N * CH * 4);
  float* xbuf   = (float*)alloc((size_t)N * CH * 4);
  int2*  pairs  = (int2*)hbuf;  // alias: pairs dead before first gemm writes hbuf

  const int nbN = (N + 255) / 256;
  const int nbE = (E + 255) / 256;
  const int nCk = (E + CHUNK - 1) / CHUNK;

  // ---- preprocessing: bucket-sorted CSR (by col) + dinv + layer-3 weight vec
  k_detect<<<1, 64, 0, stream>>>((const int*)ei, flag);
  k_init0<<<1, 256, 0, stream>>>(bcnt, S);
  kb_count<<<nCk, 256, 0, stream>>>(ei, flag, bcnt, E, N);
  kb_scan<<<1, 256, 0, stream>>>(bcnt, bbase, gcur, rowptr, NB, N);
  kb_scatter<<<nCk, 256, 0, stream>>>(ei, flag, gcur, pairs, E, N);
  kb_csr<<<NB, 256, 0, stream>>>(pairs, bcnt, bbase, counts, rowptr, src, N);
  k_dinv<<<nbN, 256, 0, stream>>>(counts, dinv, wvec, N);
  k_w<<<nbE, 256, 0, stream>>>(ei, flag, dinv, wvec, E, N);

  // ---- layers 1 & 2 (GEMM + gather-aggregate)
  dim3 ggrid((N + 63) / 64, 2);
  dim3 ablk(32, 8);
  dim3 agrid((N + 7) / 8);

  k_gemm<<<ggrid, 256, 0, stream>>>(x, W1, dinv, hbuf, N);
  k_agg4<<<agrid, ablk, 0, stream>>>(hbuf, dinv, rowptr, src, b1, xbuf, N);
  k_gemm<<<ggrid, 256, 0, stream>>>(xbuf, W2, dinv, hbuf, N);
  k_agg4<<<agrid, ablk, 0, stream>>>(hbuf, dinv, rowptr, src, b2, xbuf, N);

  // ---- layer 3 collapsed: u = sum_c w*dinv*h2[c,:]; S=(u/N)@W3; sigmoid
  k_usum<<<256, dim3(CH, 2), 0, stream>>>(xbuf, wvec, dinv, S, N);
  k_final<<<1, CH, 0, stream>>>(S, W3, b3, Wl, bl, out, 1.0f / (float)N);
}

// Round 5
// 460.198 us; speedup vs baseline: 1.8399x; 1.2476x over previous
//
#include <hip/hip_runtime.h>

#define CH 128
#define CHUNK 4096

// ---------------------------------------------------------------- bf16 helpers

__device__ __forceinline__ unsigned bfpack2(float a, float b) {
  unsigned ua = __float_as_uint(a);
  ua += 0x7FFF + ((ua >> 16) & 1);
  unsigned ub = __float_as_uint(b);
  ub += 0x7FFF + ((ub >> 16) & 1);
  return (ua >> 16) | (ub & 0xFFFF0000u);
}

__device__ __forceinline__ float2 bfunpack2(unsigned w) {
  return make_float2(__uint_as_float(w << 16), __uint_as_float(w & 0xFFFF0000u));
}

// ---------------------------------------------------------------- utilities

__device__ __forceinline__ int edge_at(const void* ei, long long i, int is64) {
  if (is64) return (int)((const long long*)ei)[i];
  return ((const int*)ei)[i];
}

__global__ void k_detect(const int* ei, int* flag) {
  if (blockIdx.x == 0 && threadIdx.x == 0) {
    int is64 = 1;
    for (int k = 1; k < 128; k += 2)
      if (ei[k] != 0) { is64 = 0; break; }
    *flag = is64;
  }
}

// zero wp[N], S[CH], bcnt[256]
__global__ void k_init(float* wp, float* S, int* bcnt, int N) {
  int i = blockIdx.x * 256 + threadIdx.x;
  if (i < N) wp[i] = 0.f;
  if (blockIdx.x == 0) {
    int t = threadIdx.x;
    bcnt[t] = 0;
    if (t < CH) S[t] = 0.f;
  }
}

// P1: per-bucket edge counts (bucket = c >> 8)
__global__ __launch_bounds__(256) void kb_count(const void* ei, const int* flag,
                                                int* bcnt, int E, int N) {
  __shared__ int hist[256];
  int t = threadIdx.x;
  hist[t] = 0;
  __syncthreads();
  int f = *flag;
  for (int e = blockIdx.x * 256 + t; e < E; e += gridDim.x * 256) {
    int r = edge_at(ei, e, f);
    int c = edge_at(ei, (long long)E + e, f);
    if ((unsigned)r < (unsigned)N && (unsigned)c < (unsigned)N)
      atomicAdd(&hist[c >> 8], 1);
  }
  __syncthreads();
  if (hist[t] > 0) atomicAdd(&bcnt[t], hist[t]);
}

// P2: scan bucket counts -> bases + cursors; rowptr[N]=total
__global__ void kb_scan(const int* bcnt, int* bbase, int* gcursor, int* rowptr,
                        int NB, int N) {
  __shared__ int tmp[256];
  int t = threadIdx.x;
  int v = (t < NB) ? bcnt[t] : 0;
  tmp[t] = v;
  __syncthreads();
  for (int off = 1; off < 256; off <<= 1) {
    int u = (t >= off) ? tmp[t - off] : 0;
    __syncthreads();
    tmp[t] += u;
    __syncthreads();
  }
  int excl = tmp[t] - v;
  bbase[t] = excl;
  gcursor[t] = excl;
  if (t == 255) rowptr[N] = tmp[255];
}

// P3: bucket-sort edges into pairs[] via LDS staging
__global__ __launch_bounds__(256) void kb_scatter(const void* ei, const int* flag,
                                                  int* gcursor, int2* pairs,
                                                  int E, int N) {
  __shared__ int hist[256], lbase[256], lcur[256], gbl[256], tmp[256];
  __shared__ int2 stage[CHUNK];
  int t = threadIdx.x;
  int e0 = blockIdx.x * CHUNK;
  int f = *flag;
  hist[t] = 0;
  __syncthreads();
  int rr[16], cc[16];
#pragma unroll
  for (int k = 0; k < 16; ++k) {
    int e = e0 + k * 256 + t;
    rr[k] = 0; cc[k] = -1;
    if (e < E) {
      int r = edge_at(ei, e, f);
      int c = edge_at(ei, (long long)E + e, f);
      if ((unsigned)r < (unsigned)N && (unsigned)c < (unsigned)N) {
        rr[k] = r; cc[k] = c;
        atomicAdd(&hist[c >> 8], 1);
      }
    }
  }
  __syncthreads();
  int v = hist[t];
  tmp[t] = v;
  __syncthreads();
  for (int off = 1; off < 256; off <<= 1) {
    int u = (t >= off) ? tmp[t - off] : 0;
    __syncthreads();
    tmp[t] += u;
    __syncthreads();
  }
  lbase[t] = tmp[t] - v;
  lcur[t] = tmp[t] - v;
  if (v > 0) gbl[t] = atomicAdd(&gcursor[t], v);
  __syncthreads();
#pragma unroll
  for (int k = 0; k < 16; ++k) {
    if (cc[k] >= 0) {
      int b = cc[k] >> 8;
      int pos = atomicAdd(&lcur[b], 1);
      stage[pos] = make_int2(rr[k], cc[k]);
    }
  }
  __syncthreads();
  int n = tmp[255];
  for (int i = t; i < n; i += 256) {
    int2 p = stage[i];
    int b = p.y >> 8;
    pairs[gbl[b] + (i - lbase[b])] = p;
  }
}

// P4: per-bucket CSR build + dinv + wp accumulation (w = dinv + wp).
__global__ __launch_bounds__(256) void kb_csr(const int2* __restrict__ pairs,
                                              const int* __restrict__ bcnt,
                                              const int* __restrict__ bbase,
                                              int* rowptr, int* src,
                                              float* dinv, float* wp, int N) {
  __shared__ int hist[256], lbase[256], lcur[256], tmp[256];
  __shared__ float dl[256];
  int t = threadIdx.x;
  int b = blockIdx.x;
  int node0 = b << 8;
  int nn = min(256, N - node0);
  int base = bbase[b];
  int cnt = bcnt[b];
  hist[t] = 0;
  __syncthreads();
  for (int j = t; j < cnt; j += 256)
    atomicAdd(&hist[pairs[base + j].y - node0], 1);
  __syncthreads();
  int v = hist[t];
  dl[t] = rsqrtf((float)(v + 1));  // +1 self-loop
  tmp[t] = v;
  __syncthreads();
  for (int off = 1; off < 256; off <<= 1) {
    int u = (t >= off) ? tmp[t - off] : 0;
    __syncthreads();
    tmp[t] += u;
    __syncthreads();
  }
  lbase[t] = tmp[t] - v;
  lcur[t] = tmp[t] - v;
  __syncthreads();
  if (t < nn) {
    rowptr[node0 + t] = base + lbase[t];
    dinv[node0 + t] = dl[t];
  }
  for (int j = t; j < cnt; j += 256) {
    int2 p = pairs[base + j];
    int pos = atomicAdd(&lcur[p.y - node0], 1);
    src[base + pos] = p.x;
    atomicAdd(&wp[p.x], dl[p.y - node0]);  // w[r] += dinv[c]
  }
}

// ---------------------------------------------------------------- GEMMs
// Cb[r,:] = bf16( dinv[r] * (A[r,:] @ W) ), W fp32 128x128

__global__ __launch_bounds__(256) void k_gemm_f32(const float* __restrict__ A,
                                                  const float* __restrict__ W,
                                                  const float* __restrict__ dinv,
                                                  uint2* __restrict__ Cb, int N) {
  __shared__ float As[64][128];
  __shared__ float Bs[128][64];
  int tid = threadIdx.x;
  int row0 = blockIdx.x * 64;
  int col0 = blockIdx.y * 64;
  {
    int k4 = tid & 31, m = tid >> 5;
    for (int mm = m; mm < 64; mm += 8) {
      int gr = row0 + mm;
      float4 v = make_float4(0.f, 0.f, 0.f, 0.f);
      if (gr < N) v = ((const float4*)A)[(size_t)gr * 32 + k4];
      *(float4*)&As[mm][k4 * 4] = v;
    }
    int n4 = tid & 15, kr = tid >> 4;
    for (int kk = kr; kk < 128; kk += 16) {
      float4 v = ((const float4*)W)[(size_t)kk * 32 + (col0 >> 2) + n4];
      *(float4*)&Bs[kk][n4 * 4] = v;
    }
  }
  __syncthreads();
  int tx = tid & 15, ty = tid >> 4;
  int m0 = ty * 4, n0 = tx * 4;
  float acc[4][4] = {};
#pragma unroll 8
  for (int k = 0; k < 128; ++k) {
    int kk = (k + ty * 33) & 127;
    float a0 = As[m0 + 0][kk], a1 = As[m0 + 1][kk];
    float a2 = As[m0 + 2][kk], a3 = As[m0 + 3][kk];
    float4 b = *(const float4*)&Bs[kk][n0];
    acc[0][0] += a0 * b.x; acc[0][1] += a0 * b.y; acc[0][2] += a0 * b.z; acc[0][3] += a0 * b.w;
    acc[1][0] += a1 * b.x; acc[1][1] += a1 * b.y; acc[1][2] += a1 * b.z; acc[1][3] += a1 * b.w;
    acc[2][0] += a2 * b.x; acc[2][1] += a2 * b.y; acc[2][2] += a2 * b.z; acc[2][3] += a2 * b.w;
    acc[3][0] += a3 * b.x; acc[3][1] += a3 * b.y; acc[3][2] += a3 * b.z; acc[3][3] += a3 * b.w;
  }
#pragma unroll
  for (int i = 0; i < 4; ++i) {
    int gr = row0 + m0 + i;
    if (gr < N) {
      float s = dinv[gr];
      unsigned p0 = bfpack2(acc[i][0] * s, acc[i][1] * s);
      unsigned p1 = bfpack2(acc[i][2] * s, acc[i][3] * s);
      Cb[(size_t)gr * 32 + ((col0 + n0) >> 2)] = make_uint2(p0, p1);
    }
  }
}

__global__ __launch_bounds__(256) void k_gemm_bf16(const uint4* __restrict__ Ab,
                                                   const float* __restrict__ W,
                                                   const float* __restrict__ dinv,
                                                   uint2* __restrict__ Cb, int N) {
  __shared__ float As[64][128];
  __shared__ float Bs[128][64];
  int tid = threadIdx.x;
  int row0 = blockIdx.x * 64;
  int col0 = blockIdx.y * 64;
  {
    int k8 = tid & 15, m = tid >> 4;  // 16 uint4 per 128-ch bf16 row
    for (int mm = m; mm < 64; mm += 16) {
      int gr = row0 + mm;
      uint4 v = make_uint4(0, 0, 0, 0);
      if (gr < N) v = Ab[(size_t)gr * 16 + k8];
      float2 p;
      float* d = &As[mm][k8 * 8];
      p = bfunpack2(v.x); d[0] = p.x; d[1] = p.y;
      p = bfunpack2(v.y); d[2] = p.x; d[3] = p.y;
      p = bfunpack2(v.z); d[4] = p.x; d[5] = p.y;
      p = bfunpack2(v.w); d[6] = p.x; d[7] = p.y;
    }
    int n4 = tid & 15, kr = tid >> 4;
    for (int kk = kr; kk < 128; kk += 16) {
      float4 v = ((const float4*)W)[(size_t)kk * 32 + (col0 >> 2) + n4];
      *(float4*)&Bs[kk][n4 * 4] = v;
    }
  }
  __syncthreads();
  int tx = tid & 15, ty = tid >> 4;
  int m0 = ty * 4, n0 = tx * 4;
  float acc[4][4] = {};
#pragma unroll 8
  for (int k = 0; k < 128; ++k) {
    int kk = (k + ty * 33) & 127;
    float a0 = As[m0 + 0][kk], a1 = As[m0 + 1][kk];
    float a2 = As[m0 + 2][kk], a3 = As[m0 + 3][kk];
    float4 b = *(const float4*)&Bs[kk][n0];
    acc[0][0] += a0 * b.x; acc[0][1] += a0 * b.y; acc[0][2] += a0 * b.z; acc[0][3] += a0 * b.w;
    acc[1][0] += a1 * b.x; acc[1][1] += a1 * b.y; acc[1][2] += a1 * b.z; acc[1][3] += a1 * b.w;
    acc[2][0] += a2 * b.x; acc[2][1] += a2 * b.y; acc[2][2] += a2 * b.z; acc[2][3] += a2 * b.w;
    acc[3][0] += a3 * b.x; acc[3][1] += a3 * b.y; acc[3][2] += a3 * b.z; acc[3][3] += a3 * b.w;
  }
#pragma unroll
  for (int i = 0; i < 4; ++i) {
    int gr = row0 + m0 + i;
    if (gr < N) {
      float s = dinv[gr];
      unsigned p0 = bfpack2(acc[i][0] * s, acc[i][1] * s);
      unsigned p1 = bfpack2(acc[i][2] * s, acc[i][3] * s);
      Cb[(size_t)gr * 32 + ((col0 + n0) >> 2)] = make_uint2(p0, p1);
    }
  }
}

// ---------------------------------------------------------------- aggregate (bf16)
// out[c,:] = bf16(relu(dinv[c]*(hh[c,:] + sum_{r} hh[r,:]) + bias))
// Row = 256 B bf16: 16 lanes x uint4; 16 node slots per 256-thread block.
__global__ __launch_bounds__(256) void k_aggb(const uint4* __restrict__ hh,
                                              const float* __restrict__ dinv,
                                              const int* __restrict__ rowptr,
                                              const int* __restrict__ src,
                                              const float* __restrict__ bias,
                                              uint4* __restrict__ outb, int N) {
  int tx = threadIdx.x;  // 0..15: 8-channel chunk
  int ty = threadIdx.y;  // 0..15: node slot
  float bv[8];
#pragma unroll
  for (int i = 0; i < 8; ++i) bv[i] = bias[tx * 8 + i];

  for (int c = blockIdx.x * 16 + ty; c < N; c += gridDim.x * 16) {
    float acc[8];
    {
      uint4 v = hh[(size_t)c * 16 + tx];  // self-loop
      float2 p;
      p = bfunpack2(v.x); acc[0] = p.x; acc[1] = p.y;
      p = bfunpack2(v.y); acc[2] = p.x; acc[3] = p.y;
      p = bfunpack2(v.z); acc[4] = p.x; acc[5] = p.y;
      p = bfunpack2(v.w); acc[6] = p.x; acc[7] = p.y;
    }
    int j = rowptr[c], je = rowptr[c + 1];
    for (; j + 8 <= je; j += 8) {
      int r0 = src[j + 0], r1 = src[j + 1], r2 = src[j + 2], r3 = src[j + 3];
      int r4 = src[j + 4], r5 = src[j + 5], r6 = src[j + 6], r7 = src[j + 7];
      uint4 v0 = hh[(size_t)r0 * 16 + tx];
      uint4 v1 = hh[(size_t)r1 * 16 + tx];
      uint4 v2 = hh[(size_t)r2 * 16 + tx];
      uint4 v3 = hh[(size_t)r3 * 16 + tx];
      uint4 v4 = hh[(size_t)r4 * 16 + tx];
      uint4 v5 = hh[(size_t)r5 * 16 + tx];
      uint4 v6 = hh[(size_t)r6 * 16 + tx];
      uint4 v7 = hh[(size_t)r7 * 16 + tx];
#pragma unroll
      for (int q = 0; q < 8; ++q) {
        uint4 v = (q == 0) ? v0 : (q == 1) ? v1 : (q == 2) ? v2 : (q == 3) ? v3
                 : (q == 4) ? v4 : (q == 5) ? v5 : (q == 6) ? v6 : v7;
        float2 p;
        p = bfunpack2(v.x); acc[0] += p.x; acc[1] += p.y;
        p = bfunpack2(v.y); acc[2] += p.x; acc[3] += p.y;
        p = bfunpack2(v.z); acc[4] += p.x; acc[5] += p.y;
        p = bfunpack2(v.w); acc[6] += p.x; acc[7] += p.y;
      }
    }
    for (; j < je; ++j) {
      uint4 v = hh[(size_t)src[j] * 16 + tx];
      float2 p;
      p = bfunpack2(v.x); acc[0] += p.x; acc[1] += p.y;
      p = bfunpack2(v.y); acc[2] += p.x; acc[3] += p.y;
      p = bfunpack2(v.z); acc[4] += p.x; acc[5] += p.y;
      p = bfunpack2(v.w); acc[6] += p.x; acc[7] += p.y;
    }
    float s = dinv[c];
    float o[8];
#pragma unroll
    for (int i = 0; i < 8; ++i) o[i] = fmaxf(acc[i] * s + bv[i], 0.f);
    uint4 ov;
    ov.x = bfpack2(o[0], o[1]);
    ov.y = bfpack2(o[2], o[3]);
    ov.z = bfpack2(o[4], o[5]);
    ov.w = bfpack2(o[6], o[7]);
    outb[(size_t)c * 16 + tx] = ov;
  }
}

// ---------------------------------------------------------------- layer-3 collapse
// u[ch] = sum_c (dinv[c]+wp[c])*dinv[c] * xb[c,ch]
__global__ __launch_bounds__(256) void k_usumb(const uint4* __restrict__ xb,
                                               const float* __restrict__ wp,
                                               const float* __restrict__ dinv,
                                               float* __restrict__ u, int N) {
  __shared__ float red[16][CH];
  int tx = threadIdx.x;  // 0..15
  int ty = threadIdx.y;  // 0..15
  float acc[8] = {};
  for (int c = blockIdx.x * 16 + ty; c < N; c += gridDim.x * 16) {
    float d = dinv[c];
    float wt = (d + wp[c]) * d;
    uint4 v = xb[(size_t)c * 16 + tx];
    float2 p;
    p = bfunpack2(v.x); acc[0] += wt * p.x; acc[1] += wt * p.y;
    p = bfunpack2(v.y); acc[2] += wt * p.x; acc[3] += wt * p.y;
    p = bfunpack2(v.z); acc[4] += wt * p.x; acc[5] += wt * p.y;
    p = bfunpack2(v.w); acc[6] += wt * p.x; acc[7] += wt * p.y;
  }
#pragma unroll
  for (int i = 0; i < 8; ++i) red[ty][tx * 8 + i] = acc[i];
  __syncthreads();
  for (int s = 8; s > 0; s >>= 1) {
    if (ty < s) {
#pragma unroll
      for (int i = 0; i < 8; ++i) red[ty][tx * 8 + i] += red[ty + s][tx * 8 + i];
    }
    __syncthreads();
  }
  if (ty == 0) {
#pragma unroll
    for (int i = 0; i < 8; ++i) atomicAdd(&u[tx * 8 + i], red[0][tx * 8 + i]);
  }
}

// ---------------------------------------------------------------- epilogue
__global__ void k_final(const float* __restrict__ u, const float* __restrict__ W3,
                        const float* __restrict__ b3, const float* __restrict__ Wl,
                        const float* __restrict__ bl, float* __restrict__ out,
                        float invN) {
  __shared__ float us[CH];
  __shared__ float red[CH];
  int t = threadIdx.x;
  us[t] = u[t] * invN;
  __syncthreads();
  float s = 0.f;
  for (int k = 0; k < CH; ++k) s += us[k] * W3[(size_t)k * CH + t];
  float g = s + b3[t];
  red[t] = g * Wl[t];
  __syncthreads();
  for (int off = 64; off > 0; off >>= 1) {
    if (t < off) red[t] += red[t + off];
    __syncthreads();
  }
  if (t == 0) out[0] = 1.f / (1.f + expf(-(red[0] + bl[0])));
}

// ---------------------------------------------------------------- launch

extern "C" void kernel_launch(void* const* d_in, const int* in_sizes, int n_in,
                              void* d_out, int out_size, void* d_ws, size_t ws_size,
                              hipStream_t stream) {
  const float* x  = (const float*)d_in[0];
  const void*  ei = d_in[1];
  const float* W1 = (const float*)d_in[3];
  const float* b1 = (const float*)d_in[4];
  const float* W2 = (const float*)d_in[5];
  const float* b2 = (const float*)d_in[6];
  const float* W3 = (const float*)d_in[7];
  const float* b3 = (const float*)d_in[8];
  const float* Wl = (const float*)d_in[9];
  const float* bl = (const float*)d_in[10];
  float* out = (float*)d_out;

  const int N = in_sizes[0] / CH;
  const int E = in_sizes[1] / 2;
  const int NB = (N + 255) >> 8;

  char* ws = (char*)d_ws;
  size_t off = 0;
  auto alloc = [&](size_t bytes) -> void* {
    void* p = ws + off;
    off += (bytes + 511) & ~(size_t)511;
    return p;
  };
  int*   flag   = (int*)alloc(4);
  float* dinv   = (float*)alloc((size_t)N * 4);
  float* wp     = (float*)alloc((size_t)N * 4);
  int*   rowptr = (int*)alloc((size_t)(N + 1) * 4);
  int*   bcnt   = (int*)alloc(256 * 4);
  int*   bbase  = (int*)alloc(256 * 4);
  int*   gcur   = (int*)alloc(256 * 4);
  float* S      = (float*)alloc(CH * 4);
  int*   src    = (int*)alloc((size_t)E * 4);
  int2*  pairs  = (int2*)alloc((size_t)E * 8);
  uint4* hbuf   = (uint4*)alloc((size_t)N * CH * 2);  // bf16 rows
  uint4* xbuf   = (uint4*)alloc((size_t)N * CH * 2);  // bf16 rows

  const int nbN = (N + 255) / 256;
  const int nCk = (E + CHUNK - 1) / CHUNK;

  // ---- preprocessing: bucket CSR + dinv + wp (layer-3 weights)
  k_detect<<<1, 64, 0, stream>>>((const int*)ei, flag);
  k_init<<<nbN, 256, 0, stream>>>(wp, S, bcnt, N);
  kb_count<<<nCk, 256, 0, stream>>>(ei, flag, bcnt, E, N);
  kb_scan<<<1, 256, 0, stream>>>(bcnt, bbase, gcur, rowptr, NB, N);
  kb_scatter<<<nCk, 256, 0, stream>>>(ei, flag, gcur, pairs, E, N);
  kb_csr<<<NB, 256, 0, stream>>>(pairs, bcnt, bbase, rowptr, src, dinv, wp, N);

  // ---- layers 1 & 2
  dim3 ggrid((N + 63) / 64, 2);
  dim3 ablk(16, 16);
  dim3 agrid((N + 15) / 16);

  k_gemm_f32<<<ggrid, 256, 0, stream>>>(x, W1, dinv, (uint2*)hbuf, N);
  k_aggb<<<agrid, ablk, 0, stream>>>(hbuf, dinv, rowptr, src, b1, xbuf, N);
  k_gemm_bf16<<<ggrid, 256, 0, stream>>>(xbuf, W2, dinv, (uint2*)hbuf, N);
  k_aggb<<<agrid, ablk, 0, stream>>>(hbuf, dinv, rowptr, src, b2, xbuf, N);

  // ---- layer 3 collapsed
  k_usumb<<<128, ablk, 0, stream>>>(xbuf, wp, dinv, S, N);
  k_final<<<1, CH, 0, stream>>>(S, W3, b3, Wl, bl, out, 1.0f / (float)N);
}